// Round 3
// baseline (1597.671 us; speedup 1.0000x reference)
//
#include <hip/hip_runtime.h>

// GNN1: 3x GraphConv(add) + linear head on MI355X.
// R3: XCD-pinned column-sliced aggregation (blockIdx%8 -> XCD, 32-dim slice
// = 3.2MB fits per-XCD L2), plane-layout h (written by GEMM epilogue), u16 csr.

typedef unsigned short u16;
typedef unsigned int u32;

#define NN 50000
#define NE 1600000
#define MPAD 50176
#define GRID_M ((NN + 127) / 128)  // 391
#define PLANE ((size_t)MPAD * 256)

using frag8 = __attribute__((ext_vector_type(8))) short;
using f32x4 = __attribute__((ext_vector_type(4))) float;

__device__ __forceinline__ u16 f2bf(float f) {
  u32 u = __float_as_uint(f);
  u32 r = u + 0x7fffu + ((u >> 16) & 1u);
  return (u16)(r >> 16);
}
__device__ __forceinline__ float lo2f(u32 u) { return __uint_as_float(u << 16); }
__device__ __forceinline__ float hi2f(u32 u) { return __uint_as_float(u & 0xffff0000u); }
__device__ __forceinline__ u32 pack2(float a, float b) {
  return (u32)f2bf(a) | ((u32)f2bf(b) << 16);
}

__device__ __forceinline__ void g2l16(const void* g, void* l) {
  __builtin_amdgcn_global_load_lds((const __attribute__((address_space(1))) void*)g,
                                   (__attribute__((address_space(3))) void*)l, 16, 0, 0);
}

// ---------------- CSR build (simple, multi-block scan) ----------------

__global__ void zero_i32(int* p, int n) {
  int i = blockIdx.x * 256 + threadIdx.x;
  if (i < n) p[i] = 0;
}

__global__ void copy_i32(const int* __restrict__ a, int* __restrict__ b, int n) {
  int i = blockIdx.x * 256 + threadIdx.x;
  if (i < n) b[i] = a[i];
}

__global__ void hist_k(const int* __restrict__ dst, int* __restrict__ deg, int ne) {
  int i = blockIdx.x * 256 + threadIdx.x;
  if (i < ne) atomicAdd(&deg[dst[i]], 1);
}

__global__ void scan1_k(const int* __restrict__ deg, int* __restrict__ rs,
                        int* __restrict__ bsum, int n) {
  __shared__ int sh[256];
  const int t = threadIdx.x;
  const int i0 = blockIdx.x * 1024 + t * 4;
  int v[4];
#pragma unroll
  for (int j = 0; j < 4; ++j) v[j] = (i0 + j < n) ? deg[i0 + j] : 0;
  int s = v[0] + v[1] + v[2] + v[3];
  sh[t] = s;
  __syncthreads();
  for (int off = 1; off < 256; off <<= 1) {
    int tmp = (t >= off) ? sh[t - off] : 0;
    __syncthreads();
    sh[t] += tmp;
    __syncthreads();
  }
  int run = sh[t] - s;
#pragma unroll
  for (int j = 0; j < 4; ++j) {
    if (i0 + j < n) rs[i0 + j] = run;
    run += v[j];
  }
  if (t == 255) bsum[blockIdx.x] = sh[255];
}

__global__ void scan2_k(int* __restrict__ bsum, int* __restrict__ bex, int nb) {
  __shared__ int sh[64];
  const int t = threadIdx.x;
  int v = (t < nb) ? bsum[t] : 0;
  sh[t] = v;
  __syncthreads();
  for (int off = 1; off < 64; off <<= 1) {
    int tmp = (t >= off) ? sh[t - off] : 0;
    __syncthreads();
    sh[t] += tmp;
    __syncthreads();
  }
  bex[t] = sh[t] - v;
}

__global__ void scan3_k(int* __restrict__ rs, const int* __restrict__ bex, int n) {
  const int i0 = blockIdx.x * 1024 + threadIdx.x * 4;
  const int add = bex[blockIdx.x];
#pragma unroll
  for (int j = 0; j < 4; ++j)
    if (i0 + j < n) rs[i0 + j] += add;
  if (blockIdx.x == 0 && threadIdx.x == 0) rs[n] = NE;
}

__global__ void fill_k(const int* __restrict__ src, const int* __restrict__ dst,
                       int* __restrict__ cur, u16* __restrict__ csr, int ne) {
  int i = blockIdx.x * 256 + threadIdx.x;
  if (i < ne) {
    int p = atomicAdd(&cur[dst[i]], 1);
    csr[p] = (u16)src[i];
  }
}

// ---------------- dtype conversion ----------------

// x f32 [NN][128] -> bf16 into aggx[node][256] upper half (offset 128)
__global__ void f2bf_x(const float4* __restrict__ in, u16* __restrict__ out, int n4) {
  int i = blockIdx.x * 256 + threadIdx.x;
  if (i < n4) {
    float4 v = in[i];
    int node = i >> 5;
    int w = i & 31;
    uint2 o;
    o.x = pack2(v.x, v.y);
    o.y = pack2(v.z, v.w);
    *(uint2*)(out + (size_t)node * 256 + 128 + w * 4) = o;
  }
}

__global__ void wtrans(const float* __restrict__ Wa, int Ka, const float* __restrict__ Wb,
                       int Kb, int N, u16* __restrict__ out) {
  int idx = blockIdx.x * 256 + threadIdx.x;
  int Kt = Ka + Kb;
  if (idx >= N * Kt) return;
  int n = idx / Kt;
  int k = idx - n * Kt;
  float v = (k < Ka) ? Wa[(size_t)k * N + n] : Wb[(size_t)(k - Ka) * N + n];
  out[idx] = f2bf(v);
}

// ---------------- layer-1 aggregation: one wave per node, 128 dims ----------------

__global__ __launch_bounds__(256) void agg128_k(const u16* __restrict__ H,  // +128 offset rows, ld 256
                                                u16* __restrict__ Out,      // ld 256, offset 0
                                                const int* __restrict__ rs,
                                                const u16* __restrict__ csr, int n) {
  int w = (blockIdx.x * 256 + threadIdx.x) >> 6;
  int lane = threadIdx.x & 63;
  if (w >= n) return;
  int beg = rs[w], end = rs[w + 1];
  float a0 = 0.f, a1 = 0.f;
  const size_t lo = (size_t)lane * 2;
  int e = beg;
  for (; e + 4 <= end; e += 4) {
    int s0 = csr[e], s1 = csr[e + 1], s2 = csr[e + 2], s3 = csr[e + 3];
    u32 v0 = *(const u32*)(H + (size_t)s0 * 256 + lo);
    u32 v1 = *(const u32*)(H + (size_t)s1 * 256 + lo);
    u32 v2 = *(const u32*)(H + (size_t)s2 * 256 + lo);
    u32 v3 = *(const u32*)(H + (size_t)s3 * 256 + lo);
    a0 += lo2f(v0); a1 += hi2f(v0);
    a0 += lo2f(v1); a1 += hi2f(v1);
    a0 += lo2f(v2); a1 += hi2f(v2);
    a0 += lo2f(v3); a1 += hi2f(v3);
  }
  for (; e < end; ++e) {
    u32 v = *(const u32*)(H + (size_t)csr[e] * 256 + lo);
    a0 += lo2f(v); a1 += hi2f(v);
  }
  *(u32*)(Out + (size_t)w * 256 + lo) = pack2(a0, a1);
}

// ---------------- 512-dim aggregation: XCD-pinned 32-dim column slices ----------------
// Hpl: 2 planes of [MPAD][256] bf16 (plane p = dims [256p,256p+256)).
// Block g = blockIdx&7 handles dims [g*32, g*32+32) of plane `pass` for 4 nodes.
// Per-XCD working set = 50000*32*2B = 3.2 MB -> fits 4 MB L2 after compulsory fill.

__global__ __launch_bounds__(256) void agg_plane(const u16* __restrict__ Hpl,
                                                 u16* __restrict__ Opl,
                                                 const int* __restrict__ rs,
                                                 const u16* __restrict__ csr,
                                                 int pass, int n) {
  const int g = blockIdx.x & 7;
  const int chunk = blockIdx.x >> 3;
  const int wv = threadIdx.x >> 6;
  const int lane = threadIdx.x & 63;
  const int node = chunk * 4 + wv;
  if (node >= n) return;
  const int eo = lane >> 3;   // edge slot 0..7
  const int sub = lane & 7;   // 4-dim sub-chunk 0..7
  const u16* __restrict__ base = Hpl + (size_t)pass * PLANE + g * 32 + sub * 4;
  const int beg = rs[node], end = rs[node + 1];
  float a0 = 0.f, a1 = 0.f, a2 = 0.f, a3 = 0.f;
  for (int e = beg; e < end; e += 8) {
    int idx = e + eo;
    if (idx < end) {
      int s = csr[idx];
      uint2 v = *(const uint2*)(base + (size_t)s * 256);
      a0 += lo2f(v.x); a1 += hi2f(v.x);
      a2 += lo2f(v.y); a3 += hi2f(v.y);
    }
  }
  // reduce across the 8 edge slots (stride 32,16,8)
  for (int d = 32; d >= 8; d >>= 1) {
    a0 += __shfl_down(a0, d);
    a1 += __shfl_down(a1, d);
    a2 += __shfl_down(a2, d);
    a3 += __shfl_down(a3, d);
  }
  if (lane < 8) {
    uint2 o;
    o.x = pack2(a0, a1);
    o.y = pack2(a2, a3);
    *(uint2*)(Opl + (size_t)pass * PLANE + (size_t)node * 256 + g * 32 + sub * 4) = o;
  }
}

// ---------------- GEMM: C = A @ Bt^T + bias (+ReLU), bf16 MFMA ----------------
// A is given as up to 4 plane segments, each [MPAD][256] bf16, segment s covers
// virtual k in [256s, 256s+256). bf16 output written in plane layout.

template <int BN>
__global__ __launch_bounds__(256) void gemm_mfma(
    const u16* __restrict__ Ab0, const u16* __restrict__ Ab1,
    const u16* __restrict__ Ab2, const u16* __restrict__ Ab3, int Ktot,
    const u16* __restrict__ Bt, const float* __restrict__ bias, int relu,
    u16* __restrict__ out_bf, float* __restrict__ out_f32, int ldof, int M) {
  constexpr int NT = BN / 32;
  __shared__ u16 lA[128 * 32];
  __shared__ u16 lB[BN * 32];
  const int tid = threadIdx.x;
  const int lane = tid & 63;
  const int wv = tid >> 6;
  const int wm = (wv >> 1) * 64;
  const int wn = (wv & 1) * (BN / 2);
  const int m0 = blockIdx.x * 128;
  const int n0 = blockIdx.y * BN;
  const int r15 = lane & 15;
  const int quad = lane >> 4;

  f32x4 acc[4][NT];
#pragma unroll
  for (int i = 0; i < 4; ++i)
#pragma unroll
    for (int j = 0; j < NT; ++j) acc[i][j] = (f32x4){0.f, 0.f, 0.f, 0.f};

  for (int kk = 0; kk < Ktot; kk += 32) {
    const u16* Ab = (kk < 256) ? Ab0 : (kk < 512) ? Ab1 : (kk < 768) ? Ab2 : Ab3;
    const int kc0 = kk & 255;
#pragma unroll
    for (int i = 0; i < 2; ++i) {
      int li = tid + i * 256;
      int row = li >> 2;
      int kc = (li & 3) * 8;
      g2l16(Ab + (size_t)(m0 + row) * 256 + kc0 + kc, &lA[li * 8]);
    }
#pragma unroll
    for (int i = 0; i < BN / 64; ++i) {
      int li = tid + i * 256;
      int nrow = li >> 2;
      int kc = (li & 3) * 8;
      g2l16(Bt + (size_t)(n0 + nrow) * Ktot + (kk + kc), &lB[li * 8]);
    }
    __syncthreads();
    frag8 af[4], bfr[NT];
#pragma unroll
    for (int mt = 0; mt < 4; ++mt)
      af[mt] = *(const frag8*)&lA[(wm + mt * 16 + r15) * 32 + quad * 8];
#pragma unroll
    for (int nt = 0; nt < NT; ++nt)
      bfr[nt] = *(const frag8*)&lB[(wn + nt * 16 + r15) * 32 + quad * 8];
#pragma unroll
    for (int mt = 0; mt < 4; ++mt)
#pragma unroll
      for (int nt = 0; nt < NT; ++nt)
        acc[mt][nt] =
            __builtin_amdgcn_mfma_f32_16x16x32_bf16(af[mt], bfr[nt], acc[mt][nt], 0, 0, 0);
    __syncthreads();
  }

#pragma unroll
  for (int mt = 0; mt < 4; ++mt) {
    int rbase = m0 + wm + mt * 16 + quad * 4;
#pragma unroll
    for (int r = 0; r < 4; ++r) {
      int row = rbase + r;
      if (row < M) {
#pragma unroll
        for (int nt = 0; nt < NT; ++nt) {
          int c = n0 + wn + nt * 16 + r15;
          float v = acc[mt][nt][r] + bias[c];
          if (relu) v = fmaxf(v, 0.f);
          if (out_f32) out_f32[(size_t)row * ldof + c] = v;
          if (out_bf)
            out_bf[(size_t)(c >> 8) * PLANE + (size_t)row * 256 + (c & 255)] = f2bf(v);
        }
      }
    }
  }
}

// ---------------- launch ----------------

extern "C" void kernel_launch(void* const* d_in, const int* in_sizes, int n_in, void* d_out,
                              int out_size, void* d_ws, size_t ws_size, hipStream_t stream) {
  const float* x = (const float*)d_in[0];
  const float* W1r = (const float*)d_in[1];
  const float* b1 = (const float*)d_in[2];
  const float* W1o = (const float*)d_in[3];
  const float* W2r = (const float*)d_in[4];
  const float* b2 = (const float*)d_in[5];
  const float* W2o = (const float*)d_in[6];
  const float* W3r = (const float*)d_in[7];
  const float* b3 = (const float*)d_in[8];
  const float* W3o = (const float*)d_in[9];
  const float* Wl = (const float*)d_in[10];
  const float* bl = (const float*)d_in[11];
  const int* src = (const int*)d_in[12];
  const int* dst = src + NE;

  size_t off = 0;
  char* ws = (char*)d_ws;
  auto take = [&](size_t bytes) -> void* {
    void* p = ws + off;
    off = (off + bytes + 255) & ~(size_t)255;
    return p;
  };
  u16* hpA = (u16*)take((size_t)MPAD * 512 * 2);  // h1 planes, later h3 planes
  u16* hpB = (u16*)take((size_t)MPAD * 512 * 2);  // h2 planes
  u16* aggP = (u16*)take((size_t)MPAD * 512 * 2); // layer1: aggx[node][256]=agg|x; later agg planes
  u16* aggx = aggP;
  u16* wt1 = (u16*)take((size_t)512 * 256 * 2);
  u16* wt2 = (u16*)take((size_t)512 * 1024 * 2);
  u16* wt3 = (u16*)take((size_t)512 * 1024 * 2);
  u16* wtl = (u16*)take((size_t)64 * 512 * 2);
  int* deg = (int*)take((size_t)NN * 4);
  int* rs = (int*)take((size_t)(NN + 1) * 4);
  int* cur = (int*)take((size_t)NN * 4);
  int* bsum = (int*)take(64 * 4);
  int* bex = (int*)take(64 * 4);
  u16* csr = (u16*)take((size_t)NE * 2);

  float* out_logits = (float*)d_out;
  float* out_embed = out_logits + (size_t)NN * 64;

  const int NBLK = (NN + 1023) / 1024;  // 49

  // CSR by dst (u16 src entries)
  zero_i32<<<(NN + 255) / 256, 256, 0, stream>>>(deg, NN);
  hist_k<<<(NE + 255) / 256, 256, 0, stream>>>(dst, deg, NE);
  scan1_k<<<NBLK, 256, 0, stream>>>(deg, rs, bsum, NN);
  scan2_k<<<1, 64, 0, stream>>>(bsum, bex, NBLK);
  scan3_k<<<NBLK, 256, 0, stream>>>(rs, bex, NN);
  copy_i32<<<(NN + 255) / 256, 256, 0, stream>>>(rs, cur, NN);
  fill_k<<<(NE + 255) / 256, 256, 0, stream>>>(src, dst, cur, csr, NE);

  // conversions
  f2bf_x<<<(NN * 32 + 255) / 256, 256, 0, stream>>>((const float4*)x, aggx, NN * 32);
  wtrans<<<(512 * 256 + 255) / 256, 256, 0, stream>>>(W1r, 128, W1o, 128, 512, wt1);
  wtrans<<<(512 * 1024 + 255) / 256, 256, 0, stream>>>(W2r, 512, W2o, 512, 512, wt2);
  wtrans<<<(512 * 1024 + 255) / 256, 256, 0, stream>>>(W3r, 512, W3o, 512, 512, wt3);
  wtrans<<<(64 * 512 + 255) / 256, 256, 0, stream>>>(Wl, 512, Wl, 0, 64, wtl);

  const int AGG_GRID = ((NN + 3) / 4) * 8;  // 100000 blocks, g = blockIdx&7

  // layer 1: agg(x)->aggx[:,0:128]; h1 = relu([agg|x] @ W1 + b1) -> hpA planes
  agg128_k<<<(NN + 3) / 4, 256, 0, stream>>>(aggx + 128, aggx, rs, csr, NN);
  gemm_mfma<128><<<dim3(GRID_M, 4), 256, 0, stream>>>(aggx, aggx, aggx, aggx, 256, wt1, b1,
                                                      1, hpA, (float*)nullptr, 0, NN);
  // layer 2
  agg_plane<<<AGG_GRID, 256, 0, stream>>>(hpA, aggP, rs, csr, 0, NN);
  agg_plane<<<AGG_GRID, 256, 0, stream>>>(hpA, aggP, rs, csr, 1, NN);
  gemm_mfma<128><<<dim3(GRID_M, 4), 256, 0, stream>>>(aggP, aggP + PLANE, hpA, hpA + PLANE,
                                                      1024, wt2, b2, 1, hpB,
                                                      (float*)nullptr, 0, NN);
  // layer 3 (bf16 -> hpA planes, f32 embed -> d_out)
  agg_plane<<<AGG_GRID, 256, 0, stream>>>(hpB, aggP, rs, csr, 0, NN);
  agg_plane<<<AGG_GRID, 256, 0, stream>>>(hpB, aggP, rs, csr, 1, NN);
  gemm_mfma<128><<<dim3(GRID_M, 4), 256, 0, stream>>>(aggP, aggP + PLANE, hpB, hpB + PLANE,
                                                      1024, wt3, b3, 1, hpA, out_embed, 512,
                                                      NN);
  // head
  gemm_mfma<64><<<dim3(GRID_M, 1), 256, 0, stream>>>(hpA, hpA + PLANE, hpA, hpA, 512, wtl,
                                                     bl, 0, (u16*)nullptr, out_logits, 64,
                                                     NN);
}

// Round 4
// 1083.269 us; speedup vs baseline: 1.4749x; 1.4749x over previous
//
#include <hip/hip_runtime.h>

// GNN1: 3x GraphConv(add) + linear head on MI355X.
// R4: revert agg to R2 full-row gather (known 220us); GEMM -> 512-thread
// 128x256 tiles (halves A re-fetch across n-blocks); u16 csr; row-major h.

typedef unsigned short u16;
typedef unsigned int u32;

#define NN 50000
#define NE 1600000
#define MPAD 50176
#define GRID_M ((NN + 127) / 128)  // 391

using frag8 = __attribute__((ext_vector_type(8))) short;
using f32x4 = __attribute__((ext_vector_type(4))) float;

__device__ __forceinline__ u16 f2bf(float f) {
  u32 u = __float_as_uint(f);
  u32 r = u + 0x7fffu + ((u >> 16) & 1u);
  return (u16)(r >> 16);
}
__device__ __forceinline__ float lo2f(u32 u) { return __uint_as_float(u << 16); }
__device__ __forceinline__ float hi2f(u32 u) { return __uint_as_float(u & 0xffff0000u); }
__device__ __forceinline__ u32 pack2(float a, float b) {
  return (u32)f2bf(a) | ((u32)f2bf(b) << 16);
}

__device__ __forceinline__ void g2l16(const void* g, void* l) {
  __builtin_amdgcn_global_load_lds((const __attribute__((address_space(1))) void*)g,
                                   (__attribute__((address_space(3))) void*)l, 16, 0, 0);
}

// ---------------- CSR build ----------------

__global__ void zero_i32(int* p, int n) {
  int i = blockIdx.x * 256 + threadIdx.x;
  if (i < n) p[i] = 0;
}

__global__ void copy_i32(const int* __restrict__ a, int* __restrict__ b, int n) {
  int i = blockIdx.x * 256 + threadIdx.x;
  if (i < n) b[i] = a[i];
}

__global__ void hist_k(const int* __restrict__ dst, int* __restrict__ deg, int ne) {
  int i = blockIdx.x * 256 + threadIdx.x;
  if (i < ne) atomicAdd(&deg[dst[i]], 1);
}

__global__ void scan1_k(const int* __restrict__ deg, int* __restrict__ rs,
                        int* __restrict__ bsum, int n) {
  __shared__ int sh[256];
  const int t = threadIdx.x;
  const int i0 = blockIdx.x * 1024 + t * 4;
  int v[4];
#pragma unroll
  for (int j = 0; j < 4; ++j) v[j] = (i0 + j < n) ? deg[i0 + j] : 0;
  int s = v[0] + v[1] + v[2] + v[3];
  sh[t] = s;
  __syncthreads();
  for (int off = 1; off < 256; off <<= 1) {
    int tmp = (t >= off) ? sh[t - off] : 0;
    __syncthreads();
    sh[t] += tmp;
    __syncthreads();
  }
  int run = sh[t] - s;
#pragma unroll
  for (int j = 0; j < 4; ++j) {
    if (i0 + j < n) rs[i0 + j] = run;
    run += v[j];
  }
  if (t == 255) bsum[blockIdx.x] = sh[255];
}

__global__ void scan2_k(int* __restrict__ bsum, int* __restrict__ bex, int nb) {
  __shared__ int sh[64];
  const int t = threadIdx.x;
  int v = (t < nb) ? bsum[t] : 0;
  sh[t] = v;
  __syncthreads();
  for (int off = 1; off < 64; off <<= 1) {
    int tmp = (t >= off) ? sh[t - off] : 0;
    __syncthreads();
    sh[t] += tmp;
    __syncthreads();
  }
  bex[t] = sh[t] - v;
}

__global__ void scan3_k(int* __restrict__ rs, const int* __restrict__ bex, int n) {
  const int i0 = blockIdx.x * 1024 + threadIdx.x * 4;
  const int add = bex[blockIdx.x];
#pragma unroll
  for (int j = 0; j < 4; ++j)
    if (i0 + j < n) rs[i0 + j] += add;
  if (blockIdx.x == 0 && threadIdx.x == 0) rs[n] = NE;
}

__global__ void fill_k(const int* __restrict__ src, const int* __restrict__ dst,
                       int* __restrict__ cur, u16* __restrict__ csr, int ne) {
  int i = blockIdx.x * 256 + threadIdx.x;
  if (i < ne) {
    int p = atomicAdd(&cur[dst[i]], 1);
    csr[p] = (u16)src[i];
  }
}

// ---------------- dtype conversion ----------------

// x f32 [NN][128] -> bf16 into aggx[node][256] upper half (offset 128)
__global__ void f2bf_x(const float4* __restrict__ in, u16* __restrict__ out, int n4) {
  int i = blockIdx.x * 256 + threadIdx.x;
  if (i < n4) {
    float4 v = in[i];
    int node = i >> 5;
    int w = i & 31;
    uint2 o;
    o.x = pack2(v.x, v.y);
    o.y = pack2(v.z, v.w);
    *(uint2*)(out + (size_t)node * 256 + 128 + w * 4) = o;
  }
}

__global__ void wtrans(const float* __restrict__ Wa, int Ka, const float* __restrict__ Wb,
                       int Kb, int N, u16* __restrict__ out) {
  int idx = blockIdx.x * 256 + threadIdx.x;
  int Kt = Ka + Kb;
  if (idx >= N * Kt) return;
  int n = idx / Kt;
  int k = idx - n * Kt;
  float v = (k < Ka) ? Wa[(size_t)k * N + n] : Wb[(size_t)(k - Ka) * N + n];
  out[idx] = f2bf(v);
}

// ---------------- aggregation: one wave per node, full-row gather ----------------

__device__ __forceinline__ void acc8(float* a, uint4 v) {
  a[0] += lo2f(v.x); a[1] += hi2f(v.x);
  a[2] += lo2f(v.y); a[3] += hi2f(v.y);
  a[4] += lo2f(v.z); a[5] += hi2f(v.z);
  a[6] += lo2f(v.w); a[7] += hi2f(v.w);
}

template <int EPL>
__global__ __launch_bounds__(256) void agg_gather(const u16* __restrict__ H, int ldh,
                                                  u16* __restrict__ Out, int ldo,
                                                  const int* __restrict__ rs,
                                                  const u16* __restrict__ csr, int n) {
  int w = (blockIdx.x * 256 + threadIdx.x) >> 6;
  int lane = threadIdx.x & 63;
  if (w >= n) return;
  int beg = rs[w], end = rs[w + 1];
  float acc[EPL];
#pragma unroll
  for (int i = 0; i < EPL; ++i) acc[i] = 0.f;
  int e = beg;
  const size_t lo = (size_t)lane * EPL;
  if constexpr (EPL == 8) {
    for (; e + 4 <= end; e += 4) {
      int s0 = csr[e], s1 = csr[e + 1], s2 = csr[e + 2], s3 = csr[e + 3];
      uint4 v0 = *(const uint4*)(H + (size_t)s0 * ldh + lo);
      uint4 v1 = *(const uint4*)(H + (size_t)s1 * ldh + lo);
      uint4 v2 = *(const uint4*)(H + (size_t)s2 * ldh + lo);
      uint4 v3 = *(const uint4*)(H + (size_t)s3 * ldh + lo);
      acc8(acc, v0); acc8(acc, v1); acc8(acc, v2); acc8(acc, v3);
    }
    for (; e < end; ++e) {
      uint4 v = *(const uint4*)(H + (size_t)csr[e] * ldh + lo);
      acc8(acc, v);
    }
    uint4 o;
    o.x = pack2(acc[0], acc[1]); o.y = pack2(acc[2], acc[3]);
    o.z = pack2(acc[4], acc[5]); o.w = pack2(acc[6], acc[7]);
    *(uint4*)(Out + (size_t)w * ldo + lo) = o;
  } else {
    for (; e + 4 <= end; e += 4) {
      int s0 = csr[e], s1 = csr[e + 1], s2 = csr[e + 2], s3 = csr[e + 3];
      u32 v0 = *(const u32*)(H + (size_t)s0 * ldh + lo);
      u32 v1 = *(const u32*)(H + (size_t)s1 * ldh + lo);
      u32 v2 = *(const u32*)(H + (size_t)s2 * ldh + lo);
      u32 v3 = *(const u32*)(H + (size_t)s3 * ldh + lo);
      acc[0] += lo2f(v0); acc[1] += hi2f(v0);
      acc[0] += lo2f(v1); acc[1] += hi2f(v1);
      acc[0] += lo2f(v2); acc[1] += hi2f(v2);
      acc[0] += lo2f(v3); acc[1] += hi2f(v3);
    }
    for (; e < end; ++e) {
      u32 v = *(const u32*)(H + (size_t)csr[e] * ldh + lo);
      acc[0] += lo2f(v); acc[1] += hi2f(v);
    }
    *(u32*)(Out + (size_t)w * ldo + lo) = pack2(acc[0], acc[1]);
  }
}

// ---------------- GEMM 128x256 tile, 512 threads, 8 waves ----------------
// C = [A1|A2] @ Bt^T + bias (+ReLU). A1 covers k<[0,K1), A2 [K1,Ktot).
// Bt [N][Ktot] k-contiguous. Wave (wm,wn) does 64x64 via 4x4 16x16x32 MFMA.

__global__ __launch_bounds__(512, 4) void gemm256(
    const u16* __restrict__ A1, int lda1, const u16* __restrict__ A2, int lda2, int K1,
    int Ktot, const u16* __restrict__ Bt, const float* __restrict__ bias, int relu,
    u16* __restrict__ out_bf, int ldob, float* __restrict__ out_f32, int ldof, int M) {
  __shared__ u16 lA[128 * 32];
  __shared__ u16 lB[256 * 32];
  const int tid = threadIdx.x;
  const int lane = tid & 63;
  const int wv = tid >> 6;           // 0..7
  const int wm = (wv >> 2) * 64;     // 0,64
  const int wn = (wv & 3) * 64;      // 0,64,128,192
  const int n0 = blockIdx.x * 256;
  const int m0 = blockIdx.y * 128;
  const int r15 = lane & 15;
  const int quad = lane >> 4;

  f32x4 acc[4][4];
#pragma unroll
  for (int i = 0; i < 4; ++i)
#pragma unroll
    for (int j = 0; j < 4; ++j) acc[i][j] = (f32x4){0.f, 0.f, 0.f, 0.f};

  for (int kk = 0; kk < Ktot; kk += 32) {
    const u16* Ab;
    int lda;
    if (kk < K1) { Ab = A1 + kk; lda = lda1; }
    else         { Ab = A2 + (kk - K1); lda = lda2; }
    {  // A tile: 128 rows x 32 k, 512 lanes x 16B
      int row = tid >> 2;
      int kc = (tid & 3) * 8;
      g2l16(Ab + (size_t)(m0 + row) * lda + kc, &lA[tid * 8]);
    }
#pragma unroll
    for (int i = 0; i < 2; ++i) {  // B tile: 256 n-rows x 32 k
      int li = tid + i * 512;
      int nrow = li >> 2;
      int kc = (li & 3) * 8;
      g2l16(Bt + (size_t)(n0 + nrow) * Ktot + (kk + kc), &lB[li * 8]);
    }
    __syncthreads();
    frag8 af[4], bfr[4];
#pragma unroll
    for (int mt = 0; mt < 4; ++mt)
      af[mt] = *(const frag8*)&lA[(wm + mt * 16 + r15) * 32 + quad * 8];
#pragma unroll
    for (int nt = 0; nt < 4; ++nt)
      bfr[nt] = *(const frag8*)&lB[(wn + nt * 16 + r15) * 32 + quad * 8];
#pragma unroll
    for (int mt = 0; mt < 4; ++mt)
#pragma unroll
      for (int nt = 0; nt < 4; ++nt)
        acc[mt][nt] =
            __builtin_amdgcn_mfma_f32_16x16x32_bf16(af[mt], bfr[nt], acc[mt][nt], 0, 0, 0);
    __syncthreads();
  }

#pragma unroll
  for (int mt = 0; mt < 4; ++mt) {
    int rbase = m0 + wm + mt * 16 + quad * 4;
#pragma unroll
    for (int r = 0; r < 4; ++r) {
      int row = rbase + r;
      if (row < M) {
#pragma unroll
        for (int nt = 0; nt < 4; ++nt) {
          int c = n0 + wn + nt * 16 + r15;
          float v = acc[mt][nt][r] + bias[c];
          if (relu) v = fmaxf(v, 0.f);
          if (out_f32) out_f32[(size_t)row * ldof + c] = v;
          if (out_bf) out_bf[(size_t)row * ldob + c] = f2bf(v);
        }
      }
    }
  }
}

// ---------------- head GEMM 128x64 tile, 256 threads ----------------

__global__ __launch_bounds__(256) void gemm64(
    const u16* __restrict__ A1, int lda1, int Ktot, const u16* __restrict__ Bt,
    const float* __restrict__ bias, float* __restrict__ out_f32, int ldof, int M) {
  __shared__ u16 lA[128 * 32];
  __shared__ u16 lB[64 * 32];
  const int tid = threadIdx.x;
  const int lane = tid & 63;
  const int wv = tid >> 6;
  const int wm = (wv >> 1) * 64;
  const int wn = (wv & 1) * 32;
  const int m0 = blockIdx.x * 128;
  const int r15 = lane & 15;
  const int quad = lane >> 4;

  f32x4 acc[4][2];
#pragma unroll
  for (int i = 0; i < 4; ++i)
#pragma unroll
    for (int j = 0; j < 2; ++j) acc[i][j] = (f32x4){0.f, 0.f, 0.f, 0.f};

  for (int kk = 0; kk < Ktot; kk += 32) {
#pragma unroll
    for (int i = 0; i < 2; ++i) {
      int li = tid + i * 256;
      int row = li >> 2;
      int kc = (li & 3) * 8;
      g2l16(A1 + (size_t)(m0 + row) * lda1 + kk + kc, &lA[li * 8]);
    }
    {
      int nrow = tid >> 2;
      int kc = (tid & 3) * 8;
      if (tid < 256) g2l16(Bt + (size_t)nrow * Ktot + (kk + kc), &lB[tid * 8]);
    }
    __syncthreads();
    frag8 af[4], bfr[2];
#pragma unroll
    for (int mt = 0; mt < 4; ++mt)
      af[mt] = *(const frag8*)&lA[(wm + mt * 16 + r15) * 32 + quad * 8];
#pragma unroll
    for (int nt = 0; nt < 2; ++nt)
      bfr[nt] = *(const frag8*)&lB[(wn + nt * 16 + r15) * 32 + quad * 8];
#pragma unroll
    for (int mt = 0; mt < 4; ++mt)
#pragma unroll
      for (int nt = 0; nt < 2; ++nt)
        acc[mt][nt] =
            __builtin_amdgcn_mfma_f32_16x16x32_bf16(af[mt], bfr[nt], acc[mt][nt], 0, 0, 0);
    __syncthreads();
  }

#pragma unroll
  for (int mt = 0; mt < 4; ++mt) {
    int rbase = m0 + wm + mt * 16 + quad * 4;
#pragma unroll
    for (int r = 0; r < 4; ++r) {
      int row = rbase + r;
      if (row < M) {
#pragma unroll
        for (int nt = 0; nt < 2; ++nt) {
          int c = wn + nt * 16 + r15;
          out_f32[(size_t)row * ldof + c] = acc[mt][nt][r] + bias[c];
        }
      }
    }
  }
}

// ---------------- launch ----------------

extern "C" void kernel_launch(void* const* d_in, const int* in_sizes, int n_in, void* d_out,
                              int out_size, void* d_ws, size_t ws_size, hipStream_t stream) {
  const float* x = (const float*)d_in[0];
  const float* W1r = (const float*)d_in[1];
  const float* b1 = (const float*)d_in[2];
  const float* W1o = (const float*)d_in[3];
  const float* W2r = (const float*)d_in[4];
  const float* b2 = (const float*)d_in[5];
  const float* W2o = (const float*)d_in[6];
  const float* W3r = (const float*)d_in[7];
  const float* b3 = (const float*)d_in[8];
  const float* W3o = (const float*)d_in[9];
  const float* Wl = (const float*)d_in[10];
  const float* bl = (const float*)d_in[11];
  const int* src = (const int*)d_in[12];
  const int* dst = src + NE;

  size_t off = 0;
  char* ws = (char*)d_ws;
  auto take = [&](size_t bytes) -> void* {
    void* p = ws + off;
    off = (off + bytes + 255) & ~(size_t)255;
    return p;
  };
  u16* h13 = (u16*)take((size_t)MPAD * 512 * 2);   // h1, later h3
  u16* h2 = (u16*)take((size_t)MPAD * 512 * 2);    // h2
  u16* aggB = (u16*)take((size_t)MPAD * 512 * 2);  // layer1: aggx[node][256]; later agg512
  u16* aggx = aggB;
  u16* wt1 = (u16*)take((size_t)512 * 256 * 2);
  u16* wt2 = (u16*)take((size_t)512 * 1024 * 2);
  u16* wt3 = (u16*)take((size_t)512 * 1024 * 2);
  u16* wtl = (u16*)take((size_t)64 * 512 * 2);
  int* deg = (int*)take((size_t)NN * 4);
  int* rs = (int*)take((size_t)(NN + 1) * 4);
  int* cur = (int*)take((size_t)NN * 4);
  int* bsum = (int*)take(64 * 4);
  int* bex = (int*)take(64 * 4);
  u16* csr = (u16*)take((size_t)NE * 2);

  float* out_logits = (float*)d_out;
  float* out_embed = out_logits + (size_t)NN * 64;

  const int NBLK = (NN + 1023) / 1024;  // 49

  // CSR by dst
  zero_i32<<<(NN + 255) / 256, 256, 0, stream>>>(deg, NN);
  hist_k<<<(NE + 255) / 256, 256, 0, stream>>>(dst, deg, NE);
  scan1_k<<<NBLK, 256, 0, stream>>>(deg, rs, bsum, NN);
  scan2_k<<<1, 64, 0, stream>>>(bsum, bex, NBLK);
  scan3_k<<<NBLK, 256, 0, stream>>>(rs, bex, NN);
  copy_i32<<<(NN + 255) / 256, 256, 0, stream>>>(rs, cur, NN);
  fill_k<<<(NE + 255) / 256, 256, 0, stream>>>(src, dst, cur, csr, NE);

  // conversions
  f2bf_x<<<(NN * 32 + 255) / 256, 256, 0, stream>>>((const float4*)x, aggx, NN * 32);
  wtrans<<<(512 * 256 + 255) / 256, 256, 0, stream>>>(W1r, 128, W1o, 128, 512, wt1);
  wtrans<<<(512 * 1024 + 255) / 256, 256, 0, stream>>>(W2r, 512, W2o, 512, 512, wt2);
  wtrans<<<(512 * 1024 + 255) / 256, 256, 0, stream>>>(W3r, 512, W3o, 512, 512, wt3);
  wtrans<<<(64 * 512 + 255) / 256, 256, 0, stream>>>(Wl, 512, Wl, 0, 64, wtl);

  // layer 1: agg(x) -> aggx[:,0:128]; h1 = relu([agg|x] @ W1 + b1)
  agg_gather<2><<<(NN + 3) / 4, 256, 0, stream>>>(aggx + 128, 256, aggx, 256, rs, csr, NN);
  gemm256<<<dim3(2, GRID_M), 512, 0, stream>>>(aggx, 256, aggx, 256, 256, 256, wt1, b1, 1,
                                               h13, 512, (float*)nullptr, 0, NN);
  // layer 2
  agg_gather<8><<<(NN + 3) / 4, 256, 0, stream>>>(h13, 512, aggB, 512, rs, csr, NN);
  gemm256<<<dim3(2, GRID_M), 512, 0, stream>>>(aggB, 512, h13, 512, 512, 1024, wt2, b2, 1,
                                               h2, 512, (float*)nullptr, 0, NN);
  // layer 3 (bf16 h3 + f32 embed to d_out)
  agg_gather<8><<<(NN + 3) / 4, 256, 0, stream>>>(h2, 512, aggB, 512, rs, csr, NN);
  gemm256<<<dim3(2, GRID_M), 512, 0, stream>>>(aggB, 512, h2, 512, 512, 1024, wt3, b3, 1,
                                               h13, 512, out_embed, 512, NN);
  // head
  gemm64<<<GRID_M, 256, 0, stream>>>(h13, 512, 512, wtl, bl, out_logits, 64, NN);
}

// Round 5
// 895.863 us; speedup vs baseline: 1.7834x; 1.2092x over previous
//
#include <hip/hip_runtime.h>

// GNN1: 3x GraphConv(add) + linear head on MI355X.
// R5: fp8-e4m3 gather payload for 512-dim aggregation (h>=0 post-relu; per
// (row, 256-col) f32 scale from GEMM epilogue row-max). Halves agg FETCH.

typedef unsigned short u16;
typedef unsigned int u32;
typedef unsigned char u8;

#define NN 50000
#define NE 1600000
#define MPAD 50176
#define GRID_M ((NN + 127) / 128)  // 391

using frag8 = __attribute__((ext_vector_type(8))) short;
using f32x4 = __attribute__((ext_vector_type(4))) float;
using f32x2 = __attribute__((ext_vector_type(2))) float;

__device__ __forceinline__ u16 f2bf(float f) {
  u32 u = __float_as_uint(f);
  u32 r = u + 0x7fffu + ((u >> 16) & 1u);
  return (u16)(r >> 16);
}
__device__ __forceinline__ float lo2f(u32 u) { return __uint_as_float(u << 16); }
__device__ __forceinline__ float hi2f(u32 u) { return __uint_as_float(u & 0xffff0000u); }
__device__ __forceinline__ u32 pack2(float a, float b) {
  return (u32)f2bf(a) | ((u32)f2bf(b) << 16);
}

__device__ __forceinline__ void g2l16(const void* g, void* l) {
  __builtin_amdgcn_global_load_lds((const __attribute__((address_space(1))) void*)g,
                                   (__attribute__((address_space(3))) void*)l, 16, 0, 0);
}

// ---------------- CSR build ----------------

__global__ void zero_i32(int* p, int n) {
  int i = blockIdx.x * 256 + threadIdx.x;
  if (i < n) p[i] = 0;
}

__global__ void copy_i32(const int* __restrict__ a, int* __restrict__ b, int n) {
  int i = blockIdx.x * 256 + threadIdx.x;
  if (i < n) b[i] = a[i];
}

__global__ void hist_k(const int* __restrict__ dst, int* __restrict__ deg, int ne) {
  int i = blockIdx.x * 256 + threadIdx.x;
  if (i < ne) atomicAdd(&deg[dst[i]], 1);
}

__global__ void scan1_k(const int* __restrict__ deg, int* __restrict__ rs,
                        int* __restrict__ bsum, int n) {
  __shared__ int sh[256];
  const int t = threadIdx.x;
  const int i0 = blockIdx.x * 1024 + t * 4;
  int v[4];
#pragma unroll
  for (int j = 0; j < 4; ++j) v[j] = (i0 + j < n) ? deg[i0 + j] : 0;
  int s = v[0] + v[1] + v[2] + v[3];
  sh[t] = s;
  __syncthreads();
  for (int off = 1; off < 256; off <<= 1) {
    int tmp = (t >= off) ? sh[t - off] : 0;
    __syncthreads();
    sh[t] += tmp;
    __syncthreads();
  }
  int run = sh[t] - s;
#pragma unroll
  for (int j = 0; j < 4; ++j) {
    if (i0 + j < n) rs[i0 + j] = run;
    run += v[j];
  }
  if (t == 255) bsum[blockIdx.x] = sh[255];
}

__global__ void scan2_k(int* __restrict__ bsum, int* __restrict__ bex, int nb) {
  __shared__ int sh[64];
  const int t = threadIdx.x;
  int v = (t < nb) ? bsum[t] : 0;
  sh[t] = v;
  __syncthreads();
  for (int off = 1; off < 64; off <<= 1) {
    int tmp = (t >= off) ? sh[t - off] : 0;
    __syncthreads();
    sh[t] += tmp;
    __syncthreads();
  }
  bex[t] = sh[t] - v;
}

__global__ void scan3_k(int* __restrict__ rs, const int* __restrict__ bex, int n) {
  const int i0 = blockIdx.x * 1024 + threadIdx.x * 4;
  const int add = bex[blockIdx.x];
#pragma unroll
  for (int j = 0; j < 4; ++j)
    if (i0 + j < n) rs[i0 + j] += add;
  if (blockIdx.x == 0 && threadIdx.x == 0) rs[n] = NE;
}

__global__ void fill_k(const int* __restrict__ src, const int* __restrict__ dst,
                       int* __restrict__ cur, u16* __restrict__ csr, int ne) {
  int i = blockIdx.x * 256 + threadIdx.x;
  if (i < ne) {
    int p = atomicAdd(&cur[dst[i]], 1);
    csr[p] = (u16)src[i];
  }
}

// ---------------- dtype conversion ----------------

// x f32 [NN][128] -> bf16 into aggx[node][256] upper half (offset 128)
__global__ void f2bf_x(const float4* __restrict__ in, u16* __restrict__ out, int n4) {
  int i = blockIdx.x * 256 + threadIdx.x;
  if (i < n4) {
    float4 v = in[i];
    int node = i >> 5;
    int w = i & 31;
    uint2 o;
    o.x = pack2(v.x, v.y);
    o.y = pack2(v.z, v.w);
    *(uint2*)(out + (size_t)node * 256 + 128 + w * 4) = o;
  }
}

__global__ void wtrans(const float* __restrict__ Wa, int Ka, const float* __restrict__ Wb,
                       int Kb, int N, u16* __restrict__ out) {
  int idx = blockIdx.x * 256 + threadIdx.x;
  int Kt = Ka + Kb;
  if (idx >= N * Kt) return;
  int n = idx / Kt;
  int k = idx - n * Kt;
  float v = (k < Ka) ? Wa[(size_t)k * N + n] : Wb[(size_t)(k - Ka) * N + n];
  out[idx] = f2bf(v);
}

// ---------------- layer-1 aggregation: bf16, 128 dims ----------------

__global__ __launch_bounds__(256) void agg_bf128(const u16* __restrict__ H, int ldh,
                                                 u16* __restrict__ Out, int ldo,
                                                 const int* __restrict__ rs,
                                                 const u16* __restrict__ csr, int n) {
  int w = (blockIdx.x * 256 + threadIdx.x) >> 6;
  int lane = threadIdx.x & 63;
  if (w >= n) return;
  int beg = rs[w], end = rs[w + 1];
  float a0 = 0.f, a1 = 0.f;
  const size_t lo = (size_t)lane * 2;
  int e = beg;
  for (; e + 4 <= end; e += 4) {
    int s0 = csr[e], s1 = csr[e + 1], s2 = csr[e + 2], s3 = csr[e + 3];
    u32 v0 = *(const u32*)(H + (size_t)s0 * ldh + lo);
    u32 v1 = *(const u32*)(H + (size_t)s1 * ldh + lo);
    u32 v2 = *(const u32*)(H + (size_t)s2 * ldh + lo);
    u32 v3 = *(const u32*)(H + (size_t)s3 * ldh + lo);
    a0 += lo2f(v0); a1 += hi2f(v0);
    a0 += lo2f(v1); a1 += hi2f(v1);
    a0 += lo2f(v2); a1 += hi2f(v2);
    a0 += lo2f(v3); a1 += hi2f(v3);
  }
  for (; e < end; ++e) {
    u32 v = *(const u32*)(H + (size_t)csr[e] * ldh + lo);
    a0 += lo2f(v); a1 += hi2f(v);
  }
  *(u32*)(Out + (size_t)w * ldo + lo) = pack2(a0, a1);
}

// ---------------- 512-dim aggregation: fp8 payload ----------------
// H8: [MPAD][512] fp8-e4m3; sc: [MPAD][2] f32 (per 256-col half).
// value = fp8 * sc[row][col>>8]. Output bf16 [node][512].

__device__ __forceinline__ void accf8(float* a, uint2 v, float s) {
  f32x2 f01 = __builtin_amdgcn_cvt_pk_f32_fp8(v.x, false);
  f32x2 f23 = __builtin_amdgcn_cvt_pk_f32_fp8(v.x, true);
  f32x2 f45 = __builtin_amdgcn_cvt_pk_f32_fp8(v.y, false);
  f32x2 f67 = __builtin_amdgcn_cvt_pk_f32_fp8(v.y, true);
  a[0] = fmaf(f01.x, s, a[0]); a[1] = fmaf(f01.y, s, a[1]);
  a[2] = fmaf(f23.x, s, a[2]); a[3] = fmaf(f23.y, s, a[3]);
  a[4] = fmaf(f45.x, s, a[4]); a[5] = fmaf(f45.y, s, a[5]);
  a[6] = fmaf(f67.x, s, a[6]); a[7] = fmaf(f67.y, s, a[7]);
}

__global__ __launch_bounds__(256) void agg_fp8(const u8* __restrict__ H8,
                                               const float* __restrict__ sc,
                                               u16* __restrict__ Out,
                                               const int* __restrict__ rs,
                                               const u16* __restrict__ csr, int n) {
  int w = (blockIdx.x * 256 + threadIdx.x) >> 6;
  int lane = threadIdx.x & 63;
  if (w >= n) return;
  int beg = rs[w], end = rs[w + 1];
  float acc[8];
#pragma unroll
  for (int i = 0; i < 8; ++i) acc[i] = 0.f;
  const int half = lane >> 5;
  const size_t lo = (size_t)lane * 8;
  int e = beg;
  for (; e + 4 <= end; e += 4) {
    int s0 = csr[e], s1 = csr[e + 1], s2 = csr[e + 2], s3 = csr[e + 3];
    uint2 v0 = *(const uint2*)(H8 + (size_t)s0 * 512 + lo);
    uint2 v1 = *(const uint2*)(H8 + (size_t)s1 * 512 + lo);
    uint2 v2 = *(const uint2*)(H8 + (size_t)s2 * 512 + lo);
    uint2 v3 = *(const uint2*)(H8 + (size_t)s3 * 512 + lo);
    float c0 = sc[s0 * 2 + half];
    float c1 = sc[s1 * 2 + half];
    float c2 = sc[s2 * 2 + half];
    float c3 = sc[s3 * 2 + half];
    accf8(acc, v0, c0); accf8(acc, v1, c1);
    accf8(acc, v2, c2); accf8(acc, v3, c3);
  }
  for (; e < end; ++e) {
    int s0 = csr[e];
    uint2 v = *(const uint2*)(H8 + (size_t)s0 * 512 + lo);
    accf8(acc, v, sc[s0 * 2 + half]);
  }
  uint4 o;
  o.x = pack2(acc[0], acc[1]); o.y = pack2(acc[2], acc[3]);
  o.z = pack2(acc[4], acc[5]); o.w = pack2(acc[6], acc[7]);
  *(uint4*)(Out + (size_t)w * 512 + lo) = o;
}

// ---------------- GEMM 128x256 tile, 512 threads, 8 waves ----------------
// C = [A1|A2] @ Bt^T + bias (+ReLU). Optional fp8 h output with per
// (row, 256-col-block) scale (requires relu so values >= 0).

__global__ __launch_bounds__(512, 4) void gemm256(
    const u16* __restrict__ A1, int lda1, const u16* __restrict__ A2, int lda2, int K1,
    int Ktot, const u16* __restrict__ Bt, const float* __restrict__ bias, int relu,
    u16* __restrict__ out_bf, int ldob, float* __restrict__ out_f32, int ldof,
    u8* __restrict__ out_fp8, float* __restrict__ out_sc, int M) {
  __shared__ u16 lA[128 * 32];
  __shared__ u16 lB[256 * 32];
  __shared__ u32 smaxu[128];
  const int tid = threadIdx.x;
  const int lane = tid & 63;
  const int wv = tid >> 6;           // 0..7
  const int wm = (wv >> 2) * 64;     // 0,64
  const int wn = (wv & 3) * 64;      // 0,64,128,192
  const int n0 = blockIdx.x * 256;
  const int m0 = blockIdx.y * 128;
  const int r15 = lane & 15;
  const int quad = lane >> 4;

  if (tid < 128) smaxu[tid] = 0;  // covered by first K-loop __syncthreads

  f32x4 acc[4][4];
#pragma unroll
  for (int i = 0; i < 4; ++i)
#pragma unroll
    for (int j = 0; j < 4; ++j) acc[i][j] = (f32x4){0.f, 0.f, 0.f, 0.f};

  for (int kk = 0; kk < Ktot; kk += 32) {
    const u16* Ab;
    int lda;
    if (kk < K1) { Ab = A1 + kk; lda = lda1; }
    else         { Ab = A2 + (kk - K1); lda = lda2; }
    {  // A tile: 128 rows x 32 k, 512 lanes x 16B
      int row = tid >> 2;
      int kc = (tid & 3) * 8;
      g2l16(Ab + (size_t)(m0 + row) * lda + kc, &lA[tid * 8]);
    }
#pragma unroll
    for (int i = 0; i < 2; ++i) {  // B tile: 256 n-rows x 32 k
      int li = tid + i * 512;
      int nrow = li >> 2;
      int kc = (li & 3) * 8;
      g2l16(Bt + (size_t)(n0 + nrow) * Ktot + (kk + kc), &lB[li * 8]);
    }
    __syncthreads();
    frag8 af[4], bfr[4];
#pragma unroll
    for (int mt = 0; mt < 4; ++mt)
      af[mt] = *(const frag8*)&lA[(wm + mt * 16 + r15) * 32 + quad * 8];
#pragma unroll
    for (int nt = 0; nt < 4; ++nt)
      bfr[nt] = *(const frag8*)&lB[(wn + nt * 16 + r15) * 32 + quad * 8];
#pragma unroll
    for (int mt = 0; mt < 4; ++mt)
#pragma unroll
      for (int nt = 0; nt < 4; ++nt)
        acc[mt][nt] =
            __builtin_amdgcn_mfma_f32_16x16x32_bf16(af[mt], bfr[nt], acc[mt][nt], 0, 0, 0);
    __syncthreads();
  }

  // transform acc -> post-bias/relu values in place; accumulate row maxes
#pragma unroll
  for (int mt = 0; mt < 4; ++mt) {
#pragma unroll
    for (int r = 0; r < 4; ++r) {
      float rm = 0.f;
#pragma unroll
      for (int nt = 0; nt < 4; ++nt) {
        int c = n0 + wn + nt * 16 + r15;
        float v = acc[mt][nt][r] + bias[c];
        if (relu) v = fmaxf(v, 0.f);
        acc[mt][nt][r] = v;
        rm = fmaxf(rm, v);
      }
      if (out_fp8) {
        // reduce over the 16 lanes of this quad (same rows, different cols)
        rm = fmaxf(rm, __shfl_xor(rm, 1));
        rm = fmaxf(rm, __shfl_xor(rm, 2));
        rm = fmaxf(rm, __shfl_xor(rm, 4));
        rm = fmaxf(rm, __shfl_xor(rm, 8));
        if (r15 == 0) atomicMax(&smaxu[wm + mt * 16 + quad * 4 + r], __float_as_uint(rm));
      }
    }
  }
  if (out_fp8) __syncthreads();

#pragma unroll
  for (int mt = 0; mt < 4; ++mt) {
    int rloc = wm + mt * 16 + quad * 4;
#pragma unroll
    for (int r = 0; r < 4; ++r) {
      int row = m0 + rloc + r;
      if (row < M) {
        float inv = 0.f;
        if (out_fp8) {
          float s = __uint_as_float(smaxu[rloc + r]);
          inv = (s > 0.f) ? 448.f / s : 0.f;
          if (r15 == 0 && wn == 0)  // one writer per (row, half): wv 0 and 4
            out_sc[row * 2 + (n0 >> 8)] = (s > 0.f) ? s / 448.f : 0.f;
        }
#pragma unroll
        for (int nt = 0; nt < 4; ++nt) {
          int c = n0 + wn + nt * 16 + r15;
          float v = acc[mt][nt][r];
          if (out_f32) out_f32[(size_t)row * ldof + c] = v;
          if (out_bf) out_bf[(size_t)row * ldob + c] = f2bf(v);
        }
        if (out_fp8) {
          u32 u01 = (u32)__builtin_amdgcn_cvt_pk_fp8_f32(acc[mt][0][r] * inv,
                                                         acc[mt][1][r] * inv, 0, false);
          u32 u23 = (u32)__builtin_amdgcn_cvt_pk_fp8_f32(acc[mt][2][r] * inv,
                                                         acc[mt][3][r] * inv, 0, false);
          size_t rb = (size_t)row * 512 + n0 + wn + r15;
          out_fp8[rb] = (u8)(u01 & 0xff);
          out_fp8[rb + 16] = (u8)((u01 >> 8) & 0xff);
          out_fp8[rb + 32] = (u8)(u23 & 0xff);
          out_fp8[rb + 48] = (u8)((u23 >> 8) & 0xff);
        }
      }
    }
  }
}

// ---------------- head GEMM 128x64 tile, 256 threads ----------------

__global__ __launch_bounds__(256) void gemm64(
    const u16* __restrict__ A1, int lda1, int Ktot, const u16* __restrict__ Bt,
    const float* __restrict__ bias, float* __restrict__ out_f32, int ldof, int M) {
  __shared__ u16 lA[128 * 32];
  __shared__ u16 lB[64 * 32];
  const int tid = threadIdx.x;
  const int lane = tid & 63;
  const int wv = tid >> 6;
  const int wm = (wv >> 1) * 64;
  const int wn = (wv & 1) * 32;
  const int m0 = blockIdx.x * 128;
  const int r15 = lane & 15;
  const int quad = lane >> 4;

  f32x4 acc[4][2];
#pragma unroll
  for (int i = 0; i < 4; ++i)
#pragma unroll
    for (int j = 0; j < 2; ++j) acc[i][j] = (f32x4){0.f, 0.f, 0.f, 0.f};

  for (int kk = 0; kk < Ktot; kk += 32) {
#pragma unroll
    for (int i = 0; i < 2; ++i) {
      int li = tid + i * 256;
      int row = li >> 2;
      int kc = (li & 3) * 8;
      g2l16(A1 + (size_t)(m0 + row) * lda1 + kk + kc, &lA[li * 8]);
    }
    {
      int nrow = tid >> 2;
      int kc = (tid & 3) * 8;
      if (tid < 256) g2l16(Bt + (size_t)nrow * Ktot + (kk + kc), &lB[tid * 8]);
    }
    __syncthreads();
    frag8 af[4], bfr[2];
#pragma unroll
    for (int mt = 0; mt < 4; ++mt)
      af[mt] = *(const frag8*)&lA[(wm + mt * 16 + r15) * 32 + quad * 8];
#pragma unroll
    for (int nt = 0; nt < 2; ++nt)
      bfr[nt] = *(const frag8*)&lB[(wn + nt * 16 + r15) * 32 + quad * 8];
#pragma unroll
    for (int mt = 0; mt < 4; ++mt)
#pragma unroll
      for (int nt = 0; nt < 2; ++nt)
        acc[mt][nt] =
            __builtin_amdgcn_mfma_f32_16x16x32_bf16(af[mt], bfr[nt], acc[mt][nt], 0, 0, 0);
    __syncthreads();
  }

#pragma unroll
  for (int mt = 0; mt < 4; ++mt) {
    int rbase = m0 + wm + mt * 16 + quad * 4;
#pragma unroll
    for (int r = 0; r < 4; ++r) {
      int row = rbase + r;
      if (row < M) {
#pragma unroll
        for (int nt = 0; nt < 2; ++nt) {
          int c = wn + nt * 16 + r15;
          out_f32[(size_t)row * ldof + c] = acc[mt][nt][r] + bias[c];
        }
      }
    }
  }
}

// ---------------- launch ----------------

extern "C" void kernel_launch(void* const* d_in, const int* in_sizes, int n_in, void* d_out,
                              int out_size, void* d_ws, size_t ws_size, hipStream_t stream) {
  const float* x = (const float*)d_in[0];
  const float* W1r = (const float*)d_in[1];
  const float* b1 = (const float*)d_in[2];
  const float* W1o = (const float*)d_in[3];
  const float* W2r = (const float*)d_in[4];
  const float* b2 = (const float*)d_in[5];
  const float* W2o = (const float*)d_in[6];
  const float* W3r = (const float*)d_in[7];
  const float* b3 = (const float*)d_in[8];
  const float* W3o = (const float*)d_in[9];
  const float* Wl = (const float*)d_in[10];
  const float* bl = (const float*)d_in[11];
  const int* src = (const int*)d_in[12];
  const int* dst = src + NE;

  size_t off = 0;
  char* ws = (char*)d_ws;
  auto take = [&](size_t bytes) -> void* {
    void* p = ws + off;
    off = (off + bytes + 255) & ~(size_t)255;
    return p;
  };
  u16* h13 = (u16*)take((size_t)MPAD * 512 * 2);   // h1, later h3 (bf16)
  u16* h2 = (u16*)take((size_t)MPAD * 512 * 2);    // h2 (bf16)
  u16* aggB = (u16*)take((size_t)MPAD * 512 * 2);  // layer1: aggx[node][256]; later agg512
  u16* aggx = aggB;
  u8* hfp8 = (u8*)take((size_t)MPAD * 512);        // h1 fp8, reused for h2 fp8
  float* scb = (float*)take((size_t)MPAD * 2 * 4); // per (row, half) scales
  u16* wt1 = (u16*)take((size_t)512 * 256 * 2);
  u16* wt2 = (u16*)take((size_t)512 * 1024 * 2);
  u16* wt3 = (u16*)take((size_t)512 * 1024 * 2);
  u16* wtl = (u16*)take((size_t)64 * 512 * 2);
  int* deg = (int*)take((size_t)NN * 4);
  int* rs = (int*)take((size_t)(NN + 1) * 4);
  int* cur = (int*)take((size_t)NN * 4);
  int* bsum = (int*)take(64 * 4);
  int* bex = (int*)take(64 * 4);
  u16* csr = (u16*)take((size_t)NE * 2);

  float* out_logits = (float*)d_out;
  float* out_embed = out_logits + (size_t)NN * 64;

  const int NBLK = (NN + 1023) / 1024;  // 49

  // CSR by dst
  zero_i32<<<(NN + 255) / 256, 256, 0, stream>>>(deg, NN);
  hist_k<<<(NE + 255) / 256, 256, 0, stream>>>(dst, deg, NE);
  scan1_k<<<NBLK, 256, 0, stream>>>(deg, rs, bsum, NN);
  scan2_k<<<1, 64, 0, stream>>>(bsum, bex, NBLK);
  scan3_k<<<NBLK, 256, 0, stream>>>(rs, bex, NN);
  copy_i32<<<(NN + 255) / 256, 256, 0, stream>>>(rs, cur, NN);
  fill_k<<<(NE + 255) / 256, 256, 0, stream>>>(src, dst, cur, csr, NE);

  // conversions
  f2bf_x<<<(NN * 32 + 255) / 256, 256, 0, stream>>>((const float4*)x, aggx, NN * 32);
  wtrans<<<(512 * 256 + 255) / 256, 256, 0, stream>>>(W1r, 128, W1o, 128, 512, wt1);
  wtrans<<<(512 * 1024 + 255) / 256, 256, 0, stream>>>(W2r, 512, W2o, 512, 512, wt2);
  wtrans<<<(512 * 1024 + 255) / 256, 256, 0, stream>>>(W3r, 512, W3o, 512, 512, wt3);
  wtrans<<<(64 * 512 + 255) / 256, 256, 0, stream>>>(Wl, 512, Wl, 0, 64, wtl);

  // layer 1: agg(x) -> aggx[:,0:128]; h1 = relu([agg|x] @ W1 + b1) -> bf16 + fp8
  agg_bf128<<<(NN + 3) / 4, 256, 0, stream>>>(aggx + 128, 256, aggx, 256, rs, csr, NN);
  gemm256<<<dim3(2, GRID_M), 512, 0, stream>>>(aggx, 256, aggx, 256, 256, 256, wt1, b1, 1,
                                               h13, 512, (float*)nullptr, 0, hfp8, scb, NN);
  // layer 2: fp8 gather of h1; h2 -> bf16 + fp8 (reuse hfp8/scb after agg done)
  agg_fp8<<<(NN + 3) / 4, 256, 0, stream>>>(hfp8, scb, aggB, rs, csr, NN);
  gemm256<<<dim3(2, GRID_M), 512, 0, stream>>>(aggB, 512, h13, 512, 512, 1024, wt2, b2, 1,
                                               h2, 512, (float*)nullptr, 0, hfp8, scb, NN);
  // layer 3: fp8 gather of h2; h3 -> bf16 + f32 embed
  agg_fp8<<<(NN + 3) / 4, 256, 0, stream>>>(hfp8, scb, aggB, rs, csr, NN);
  gemm256<<<dim3(2, GRID_M), 512, 0, stream>>>(aggB, 512, h2, 512, 512, 1024, wt3, b3, 1,
                                               h13, 512, out_embed, 512, (u8*)nullptr,
                                               (float*)nullptr, NN);
  // head
  gemm64<<<GRID_M, 256, 0, stream>>>(h13, 512, 512, wtl, bl, out_logits, 64, NN);
}

// Round 6
// 758.368 us; speedup vs baseline: 2.1067x; 1.1813x over previous
//
#include <hip/hip_runtime.h>

// GNN1: 3x GraphConv(add) + linear head on MI355X.
// R6: binned CSR build (LDS-staged scatter, coalesced flushes) replaces
// hist/scan/fill random-scatter (was 124us fill + ~hist). fp8 agg kept.

typedef unsigned short u16;
typedef unsigned int u32;
typedef unsigned char u8;

#define NN 50000
#define NE 1600000
#define MPAD 50176
#define GRID_M ((NN + 127) / 128)  // 391
#define NBKT 98                    // 512-node buckets
#define CAP 20480                  // region capacity per bucket (mean 16327, sigma 127)
#define STG 18432                  // pass-2 LDS csr staging entries

using frag8 = __attribute__((ext_vector_type(8))) short;
using f32x4 = __attribute__((ext_vector_type(4))) float;
using f32x2 = __attribute__((ext_vector_type(2))) float;

__device__ __forceinline__ u16 f2bf(float f) {
  u32 u = __float_as_uint(f);
  u32 r = u + 0x7fffu + ((u >> 16) & 1u);
  return (u16)(r >> 16);
}
__device__ __forceinline__ float lo2f(u32 u) { return __uint_as_float(u << 16); }
__device__ __forceinline__ float hi2f(u32 u) { return __uint_as_float(u & 0xffff0000u); }
__device__ __forceinline__ u32 pack2(float a, float b) {
  return (u32)f2bf(a) | ((u32)f2bf(b) << 16);
}

__device__ __forceinline__ void g2l16(const void* g, void* l) {
  __builtin_amdgcn_global_load_lds((const __attribute__((address_space(1))) void*)g,
                                   (__attribute__((address_space(3))) void*)l, 16, 0, 0);
}

// ---------------- binned CSR build ----------------

__global__ void zero_i32(int* p, int n) {
  int i = blockIdx.x * 256 + threadIdx.x;
  if (i < n) p[i] = 0;
}

// pass 1: bin edges into per-bucket regions; LDS staging for coalesced flush
__global__ __launch_bounds__(256) void p1bin(const int* __restrict__ src,
                                             const int* __restrict__ dst,
                                             int* __restrict__ gcur,
                                             u32* __restrict__ region, int ne) {
  __shared__ u32 lbuf[NBKT * 64];
  __shared__ int lcnt[NBKT];
  __shared__ int gbase[NBKT];
  const int tid = threadIdx.x;
  if (tid < NBKT) lcnt[tid] = 0;
  __syncthreads();
  const int base = blockIdx.x * 2048;
#pragma unroll
  for (int j = 0; j < 8; ++j) {
    int i = base + j * 256 + tid;
    if (i < ne) {
      int d = dst[i];
      int s = src[i];
      int b = d >> 9;
      u32 entry = ((u32)(d & 511) << 16) | (u32)s;
      int slot = atomicAdd(&lcnt[b], 1);
      if (slot < 64) lbuf[b * 64 + slot] = entry;
      else {  // overflow (ultra-rare): direct global append
        int g = atomicAdd(&gcur[b], 1);
        region[(size_t)b * CAP + g] = entry;
      }
    }
  }
  __syncthreads();
  if (tid < NBKT) {
    int c = min(lcnt[tid], 64);
    gbase[tid] = atomicAdd(&gcur[tid], c);
  }
  __syncthreads();
  const int wv = tid >> 6, lane = tid & 63;
  for (int b = wv; b < NBKT; b += 4) {
    int c = min(lcnt[b], 64);
    int gb = gbase[b];
    for (int s2 = lane; s2 < c; s2 += 64)
      region[(size_t)b * CAP + gb + s2] = lbuf[b * 64 + s2];
  }
}

__global__ void scan98(const int* __restrict__ gcur, int* __restrict__ bbase,
                       int* __restrict__ rs) {
  if (threadIdx.x == 0) {
    int run = 0;
    for (int b = 0; b < NBKT; ++b) {
      bbase[b] = run;
      run += gcur[b];
    }
    bbase[NBKT] = run;
    rs[NN] = run;  // == NE
  }
}

// pass 2: one block per bucket -> rs + csr (coalesced via LDS staging)
__global__ __launch_bounds__(256) void p2build(const u32* __restrict__ region,
                                               const int* __restrict__ gcnt,
                                               const int* __restrict__ bbase,
                                               int* __restrict__ rs,
                                               u16* __restrict__ csr) {
  __shared__ int cnt[512];
  __shared__ int off[512];
  __shared__ int sh[256];
  __shared__ u16 stg[STG];
  const int b = blockIdx.x, tid = threadIdx.x;
  const int n0 = b * 512;
  const int nnb = min(512, NN - n0);
  const int ec = gcnt[b];
  const int gb = bbase[b];
  const u32* __restrict__ reg = region + (size_t)b * CAP;
  cnt[tid] = 0;
  cnt[tid + 256] = 0;
  __syncthreads();
  for (int i = tid; i < ec; i += 256) atomicAdd(&cnt[reg[i] >> 16], 1);
  __syncthreads();
  int c0 = cnt[2 * tid], c1 = cnt[2 * tid + 1];
  int s = c0 + c1;
  sh[tid] = s;
  __syncthreads();
  for (int o = 1; o < 256; o <<= 1) {
    int t2 = (tid >= o) ? sh[tid - o] : 0;
    __syncthreads();
    sh[tid] += t2;
    __syncthreads();
  }
  int base0 = sh[tid] - s;
  off[2 * tid] = base0;
  off[2 * tid + 1] = base0 + c0;
  __syncthreads();
  if (2 * tid < nnb) rs[n0 + 2 * tid] = gb + off[2 * tid];
  if (2 * tid + 1 < nnb) rs[n0 + 2 * tid + 1] = gb + off[2 * tid + 1];
  cnt[2 * tid] = off[2 * tid];  // reuse cnt[] as running cursors
  cnt[2 * tid + 1] = off[2 * tid + 1];
  __syncthreads();
  for (int i = tid; i < ec; i += 256) {
    u32 e = reg[i];
    int slot = atomicAdd(&cnt[e >> 16], 1);
    u16 sv = (u16)(e & 0xffff);
    if (slot < STG) stg[slot] = sv;
    else csr[gb + slot] = sv;  // staging overflow fallback
  }
  __syncthreads();
  for (int i = tid; i < ec && i < STG; i += 256) csr[gb + i] = stg[i];
}

// ---------------- dtype conversion ----------------

// x f32 [NN][128] -> bf16 into aggx[node][256] upper half (offset 128)
__global__ void f2bf_x(const float4* __restrict__ in, u16* __restrict__ out, int n4) {
  int i = blockIdx.x * 256 + threadIdx.x;
  if (i < n4) {
    float4 v = in[i];
    int node = i >> 5;
    int w = i & 31;
    uint2 o;
    o.x = pack2(v.x, v.y);
    o.y = pack2(v.z, v.w);
    *(uint2*)(out + (size_t)node * 256 + 128 + w * 4) = o;
  }
}

__global__ void wtrans(const float* __restrict__ Wa, int Ka, const float* __restrict__ Wb,
                       int Kb, int N, u16* __restrict__ out) {
  int idx = blockIdx.x * 256 + threadIdx.x;
  int Kt = Ka + Kb;
  if (idx >= N * Kt) return;
  int n = idx / Kt;
  int k = idx - n * Kt;
  float v = (k < Ka) ? Wa[(size_t)k * N + n] : Wb[(size_t)(k - Ka) * N + n];
  out[idx] = f2bf(v);
}

// ---------------- layer-1 aggregation: bf16, 128 dims ----------------

__global__ __launch_bounds__(256) void agg_bf128(const u16* __restrict__ H, int ldh,
                                                 u16* __restrict__ Out, int ldo,
                                                 const int* __restrict__ rs,
                                                 const u16* __restrict__ csr, int n) {
  int w = (blockIdx.x * 256 + threadIdx.x) >> 6;
  int lane = threadIdx.x & 63;
  if (w >= n) return;
  int beg = rs[w], end = rs[w + 1];
  float a0 = 0.f, a1 = 0.f;
  const size_t lo = (size_t)lane * 2;
  int e = beg;
  for (; e + 4 <= end; e += 4) {
    int s0 = csr[e], s1 = csr[e + 1], s2 = csr[e + 2], s3 = csr[e + 3];
    u32 v0 = *(const u32*)(H + (size_t)s0 * ldh + lo);
    u32 v1 = *(const u32*)(H + (size_t)s1 * ldh + lo);
    u32 v2 = *(const u32*)(H + (size_t)s2 * ldh + lo);
    u32 v3 = *(const u32*)(H + (size_t)s3 * ldh + lo);
    a0 += lo2f(v0); a1 += hi2f(v0);
    a0 += lo2f(v1); a1 += hi2f(v1);
    a0 += lo2f(v2); a1 += hi2f(v2);
    a0 += lo2f(v3); a1 += hi2f(v3);
  }
  for (; e < end; ++e) {
    u32 v = *(const u32*)(H + (size_t)csr[e] * ldh + lo);
    a0 += lo2f(v); a1 += hi2f(v);
  }
  *(u32*)(Out + (size_t)w * ldo + lo) = pack2(a0, a1);
}

// ---------------- 512-dim aggregation: fp8 payload ----------------

__device__ __forceinline__ void accf8(float* a, uint2 v, float s) {
  f32x2 f01 = __builtin_amdgcn_cvt_pk_f32_fp8(v.x, false);
  f32x2 f23 = __builtin_amdgcn_cvt_pk_f32_fp8(v.x, true);
  f32x2 f45 = __builtin_amdgcn_cvt_pk_f32_fp8(v.y, false);
  f32x2 f67 = __builtin_amdgcn_cvt_pk_f32_fp8(v.y, true);
  a[0] = fmaf(f01.x, s, a[0]); a[1] = fmaf(f01.y, s, a[1]);
  a[2] = fmaf(f23.x, s, a[2]); a[3] = fmaf(f23.y, s, a[3]);
  a[4] = fmaf(f45.x, s, a[4]); a[5] = fmaf(f45.y, s, a[5]);
  a[6] = fmaf(f67.x, s, a[6]); a[7] = fmaf(f67.y, s, a[7]);
}

__global__ __launch_bounds__(256) void agg_fp8(const u8* __restrict__ H8,
                                               const float* __restrict__ sc,
                                               u16* __restrict__ Out,
                                               const int* __restrict__ rs,
                                               const u16* __restrict__ csr, int n) {
  int w = (blockIdx.x * 256 + threadIdx.x) >> 6;
  int lane = threadIdx.x & 63;
  if (w >= n) return;
  int beg = rs[w], end = rs[w + 1];
  float acc[8];
#pragma unroll
  for (int i = 0; i < 8; ++i) acc[i] = 0.f;
  const int half = lane >> 5;
  const size_t lo = (size_t)lane * 8;
  int e = beg;
  for (; e + 4 <= end; e += 4) {
    int s0 = csr[e], s1 = csr[e + 1], s2 = csr[e + 2], s3 = csr[e + 3];
    uint2 v0 = *(const uint2*)(H8 + (size_t)s0 * 512 + lo);
    uint2 v1 = *(const uint2*)(H8 + (size_t)s1 * 512 + lo);
    uint2 v2 = *(const uint2*)(H8 + (size_t)s2 * 512 + lo);
    uint2 v3 = *(const uint2*)(H8 + (size_t)s3 * 512 + lo);
    float c0 = sc[s0 * 2 + half];
    float c1 = sc[s1 * 2 + half];
    float c2 = sc[s2 * 2 + half];
    float c3 = sc[s3 * 2 + half];
    accf8(acc, v0, c0); accf8(acc, v1, c1);
    accf8(acc, v2, c2); accf8(acc, v3, c3);
  }
  for (; e < end; ++e) {
    int s0 = csr[e];
    uint2 v = *(const uint2*)(H8 + (size_t)s0 * 512 + lo);
    accf8(acc, v, sc[s0 * 2 + half]);
  }
  uint4 o;
  o.x = pack2(acc[0], acc[1]); o.y = pack2(acc[2], acc[3]);
  o.z = pack2(acc[4], acc[5]); o.w = pack2(acc[6], acc[7]);
  *(uint4*)(Out + (size_t)w * 512 + lo) = o;
}

// ---------------- GEMM 128x256 tile, 512 threads, 8 waves ----------------

__global__ __launch_bounds__(512, 4) void gemm256(
    const u16* __restrict__ A1, int lda1, const u16* __restrict__ A2, int lda2, int K1,
    int Ktot, const u16* __restrict__ Bt, const float* __restrict__ bias, int relu,
    u16* __restrict__ out_bf, int ldob, float* __restrict__ out_f32, int ldof,
    u8* __restrict__ out_fp8, float* __restrict__ out_sc, int M) {
  __shared__ u16 lA[128 * 32];
  __shared__ u16 lB[256 * 32];
  __shared__ u32 smaxu[128];
  const int tid = threadIdx.x;
  const int lane = tid & 63;
  const int wv = tid >> 6;           // 0..7
  const int wm = (wv >> 2) * 64;     // 0,64
  const int wn = (wv & 3) * 64;      // 0,64,128,192
  const int n0 = blockIdx.x * 256;
  const int m0 = blockIdx.y * 128;
  const int r15 = lane & 15;
  const int quad = lane >> 4;

  if (tid < 128) smaxu[tid] = 0;  // covered by first K-loop __syncthreads

  f32x4 acc[4][4];
#pragma unroll
  for (int i = 0; i < 4; ++i)
#pragma unroll
    for (int j = 0; j < 4; ++j) acc[i][j] = (f32x4){0.f, 0.f, 0.f, 0.f};

  for (int kk = 0; kk < Ktot; kk += 32) {
    const u16* Ab;
    int lda;
    if (kk < K1) { Ab = A1 + kk; lda = lda1; }
    else         { Ab = A2 + (kk - K1); lda = lda2; }
    {
      int row = tid >> 2;
      int kc = (tid & 3) * 8;
      g2l16(Ab + (size_t)(m0 + row) * lda + kc, &lA[tid * 8]);
    }
#pragma unroll
    for (int i = 0; i < 2; ++i) {
      int li = tid + i * 512;
      int nrow = li >> 2;
      int kc = (li & 3) * 8;
      g2l16(Bt + (size_t)(n0 + nrow) * Ktot + (kk + kc), &lB[li * 8]);
    }
    __syncthreads();
    frag8 af[4], bfr[4];
#pragma unroll
    for (int mt = 0; mt < 4; ++mt)
      af[mt] = *(const frag8*)&lA[(wm + mt * 16 + r15) * 32 + quad * 8];
#pragma unroll
    for (int nt = 0; nt < 4; ++nt)
      bfr[nt] = *(const frag8*)&lB[(wn + nt * 16 + r15) * 32 + quad * 8];
#pragma unroll
    for (int mt = 0; mt < 4; ++mt)
#pragma unroll
      for (int nt = 0; nt < 4; ++nt)
        acc[mt][nt] =
            __builtin_amdgcn_mfma_f32_16x16x32_bf16(af[mt], bfr[nt], acc[mt][nt], 0, 0, 0);
    __syncthreads();
  }

#pragma unroll
  for (int mt = 0; mt < 4; ++mt) {
#pragma unroll
    for (int r = 0; r < 4; ++r) {
      float rm = 0.f;
#pragma unroll
      for (int nt = 0; nt < 4; ++nt) {
        int c = n0 + wn + nt * 16 + r15;
        float v = acc[mt][nt][r] + bias[c];
        if (relu) v = fmaxf(v, 0.f);
        acc[mt][nt][r] = v;
        rm = fmaxf(rm, v);
      }
      if (out_fp8) {
        rm = fmaxf(rm, __shfl_xor(rm, 1));
        rm = fmaxf(rm, __shfl_xor(rm, 2));
        rm = fmaxf(rm, __shfl_xor(rm, 4));
        rm = fmaxf(rm, __shfl_xor(rm, 8));
        if (r15 == 0) atomicMax(&smaxu[wm + mt * 16 + quad * 4 + r], __float_as_uint(rm));
      }
    }
  }
  if (out_fp8) __syncthreads();

#pragma unroll
  for (int mt = 0; mt < 4; ++mt) {
    int rloc = wm + mt * 16 + quad * 4;
#pragma unroll
    for (int r = 0; r < 4; ++r) {
      int row = m0 + rloc + r;
      if (row < M) {
        float inv = 0.f;
        if (out_fp8) {
          float s = __uint_as_float(smaxu[rloc + r]);
          inv = (s > 0.f) ? 448.f / s : 0.f;
          if (r15 == 0 && wn == 0)
            out_sc[row * 2 + (n0 >> 8)] = (s > 0.f) ? s / 448.f : 0.f;
        }
#pragma unroll
        for (int nt = 0; nt < 4; ++nt) {
          int c = n0 + wn + nt * 16 + r15;
          float v = acc[mt][nt][r];
          if (out_f32) out_f32[(size_t)row * ldof + c] = v;
          if (out_bf) out_bf[(size_t)row * ldob + c] = f2bf(v);
        }
        if (out_fp8) {
          u32 u01 = (u32)__builtin_amdgcn_cvt_pk_fp8_f32(acc[mt][0][r] * inv,
                                                         acc[mt][1][r] * inv, 0, false);
          u32 u23 = (u32)__builtin_amdgcn_cvt_pk_fp8_f32(acc[mt][2][r] * inv,
                                                         acc[mt][3][r] * inv, 0, false);
          size_t rb = (size_t)row * 512 + n0 + wn + r15;
          out_fp8[rb] = (u8)(u01 & 0xff);
          out_fp8[rb + 16] = (u8)((u01 >> 8) & 0xff);
          out_fp8[rb + 32] = (u8)(u23 & 0xff);
          out_fp8[rb + 48] = (u8)((u23 >> 8) & 0xff);
        }
      }
    }
  }
}

// ---------------- head GEMM 128x64 tile, 256 threads ----------------

__global__ __launch_bounds__(256) void gemm64(
    const u16* __restrict__ A1, int lda1, int Ktot, const u16* __restrict__ Bt,
    const float* __restrict__ bias, float* __restrict__ out_f32, int ldof, int M) {
  __shared__ u16 lA[128 * 32];
  __shared__ u16 lB[64 * 32];
  const int tid = threadIdx.x;
  const int lane = tid & 63;
  const int wv = tid >> 6;
  const int wm = (wv >> 1) * 64;
  const int wn = (wv & 1) * 32;
  const int m0 = blockIdx.x * 128;
  const int r15 = lane & 15;
  const int quad = lane >> 4;

  f32x4 acc[4][2];
#pragma unroll
  for (int i = 0; i < 4; ++i)
#pragma unroll
    for (int j = 0; j < 2; ++j) acc[i][j] = (f32x4){0.f, 0.f, 0.f, 0.f};

  for (int kk = 0; kk < Ktot; kk += 32) {
#pragma unroll
    for (int i = 0; i < 2; ++i) {
      int li = tid + i * 256;
      int row = li >> 2;
      int kc = (li & 3) * 8;
      g2l16(A1 + (size_t)(m0 + row) * lda1 + kk + kc, &lA[li * 8]);
    }
    {
      int nrow = tid >> 2;
      int kc = (tid & 3) * 8;
      if (tid < 256) g2l16(Bt + (size_t)nrow * Ktot + (kk + kc), &lB[tid * 8]);
    }
    __syncthreads();
    frag8 af[4], bfr[2];
#pragma unroll
    for (int mt = 0; mt < 4; ++mt)
      af[mt] = *(const frag8*)&lA[(wm + mt * 16 + r15) * 32 + quad * 8];
#pragma unroll
    for (int nt = 0; nt < 2; ++nt)
      bfr[nt] = *(const frag8*)&lB[(wn + nt * 16 + r15) * 32 + quad * 8];
#pragma unroll
    for (int mt = 0; mt < 4; ++mt)
#pragma unroll
      for (int nt = 0; nt < 2; ++nt)
        acc[mt][nt] =
            __builtin_amdgcn_mfma_f32_16x16x32_bf16(af[mt], bfr[nt], acc[mt][nt], 0, 0, 0);
    __syncthreads();
  }

#pragma unroll
  for (int mt = 0; mt < 4; ++mt) {
    int rbase = m0 + wm + mt * 16 + quad * 4;
#pragma unroll
    for (int r = 0; r < 4; ++r) {
      int row = rbase + r;
      if (row < M) {
#pragma unroll
        for (int nt = 0; nt < 2; ++nt) {
          int c = wn + nt * 16 + r15;
          out_f32[(size_t)row * ldof + c] = acc[mt][nt][r] + bias[c];
        }
      }
    }
  }
}

// ---------------- launch ----------------

extern "C" void kernel_launch(void* const* d_in, const int* in_sizes, int n_in, void* d_out,
                              int out_size, void* d_ws, size_t ws_size, hipStream_t stream) {
  const float* x = (const float*)d_in[0];
  const float* W1r = (const float*)d_in[1];
  const float* b1 = (const float*)d_in[2];
  const float* W1o = (const float*)d_in[3];
  const float* W2r = (const float*)d_in[4];
  const float* b2 = (const float*)d_in[5];
  const float* W2o = (const float*)d_in[6];
  const float* W3r = (const float*)d_in[7];
  const float* b3 = (const float*)d_in[8];
  const float* W3o = (const float*)d_in[9];
  const float* Wl = (const float*)d_in[10];
  const float* bl = (const float*)d_in[11];
  const int* src = (const int*)d_in[12];
  const int* dst = src + NE;

  size_t off = 0;
  char* ws = (char*)d_ws;
  auto take = [&](size_t bytes) -> void* {
    void* p = ws + off;
    off = (off + bytes + 255) & ~(size_t)255;
    return p;
  };
  u16* h13 = (u16*)take((size_t)MPAD * 512 * 2);   // h1, later h3 (bf16)
  u16* h2 = (u16*)take((size_t)MPAD * 512 * 2);    // h2 (bf16)
  u16* aggB = (u16*)take((size_t)MPAD * 512 * 2);  // layer1: aggx[node][256]; later agg512
  u16* aggx = aggB;
  u8* hfp8 = (u8*)take((size_t)MPAD * 512);        // h1 fp8, reused for h2 fp8
  float* scb = (float*)take((size_t)MPAD * 2 * 4); // per (row, half) scales
  u16* wt1 = (u16*)take((size_t)512 * 256 * 2);
  u16* wt2 = (u16*)take((size_t)512 * 1024 * 2);
  u16* wt3 = (u16*)take((size_t)512 * 1024 * 2);
  u16* wtl = (u16*)take((size_t)64 * 512 * 2);
  u32* region = (u32*)take((size_t)NBKT * CAP * 4);
  int* gcur = (int*)take(128 * 4);
  int* bbase = (int*)take(128 * 4);
  int* rs = (int*)take((size_t)(NN + 1) * 4);
  u16* csr = (u16*)take((size_t)NE * 2);

  float* out_logits = (float*)d_out;
  float* out_embed = out_logits + (size_t)NN * 64;

  // binned CSR build
  zero_i32<<<1, 128, 0, stream>>>(gcur, NBKT);
  p1bin<<<(NE + 2047) / 2048, 256, 0, stream>>>(src, dst, gcur, region, NE);
  scan98<<<1, 64, 0, stream>>>(gcur, bbase, rs);
  p2build<<<NBKT, 256, 0, stream>>>(region, gcur, bbase, rs, csr);

  // conversions
  f2bf_x<<<(NN * 32 + 255) / 256, 256, 0, stream>>>((const float4*)x, aggx, NN * 32);
  wtrans<<<(512 * 256 + 255) / 256, 256, 0, stream>>>(W1r, 128, W1o, 128, 512, wt1);
  wtrans<<<(512 * 1024 + 255) / 256, 256, 0, stream>>>(W2r, 512, W2o, 512, 512, wt2);
  wtrans<<<(512 * 1024 + 255) / 256, 256, 0, stream>>>(W3r, 512, W3o, 512, 512, wt3);
  wtrans<<<(64 * 512 + 255) / 256, 256, 0, stream>>>(Wl, 512, Wl, 0, 64, wtl);

  // layer 1: agg(x) -> aggx[:,0:128]; h1 = relu([agg|x] @ W1 + b1) -> bf16 + fp8
  agg_bf128<<<(NN + 3) / 4, 256, 0, stream>>>(aggx + 128, 256, aggx, 256, rs, csr, NN);
  gemm256<<<dim3(2, GRID_M), 512, 0, stream>>>(aggx, 256, aggx, 256, 256, 256, wt1, b1, 1,
                                               h13, 512, (float*)nullptr, 0, hfp8, scb, NN);
  // layer 2: fp8 gather of h1; h2 -> bf16 + fp8
  agg_fp8<<<(NN + 3) / 4, 256, 0, stream>>>(hfp8, scb, aggB, rs, csr, NN);
  gemm256<<<dim3(2, GRID_M), 512, 0, stream>>>(aggB, 512, h13, 512, 512, 1024, wt2, b2, 1,
                                               h2, 512, (float*)nullptr, 0, hfp8, scb, NN);
  // layer 3: fp8 gather of h2; h3 -> bf16 + f32 embed
  agg_fp8<<<(NN + 3) / 4, 256, 0, stream>>>(hfp8, scb, aggB, rs, csr, NN);
  gemm256<<<dim3(2, GRID_M), 512, 0, stream>>>(aggB, 512, h2, 512, 512, 1024, wt3, b3, 1,
                                               h13, 512, out_embed, 512, (u8*)nullptr,
                                               (float*)nullptr, NN);
  // head
  gemm64<<<GRID_M, 256, 0, stream>>>(h13, 512, 512, wtl, bl, out_logits, 64, NN);
}